// Round 3
// baseline (835.553 us; speedup 1.0000x reference)
//
#include <hip/hip_runtime.h>
#include <hip/hip_bf16.h>
#include <stdint.h>

typedef __bf16 bf16x8 __attribute__((ext_vector_type(8)));
typedef __bf16 bf16x2 __attribute__((ext_vector_type(2)));
typedef float  f32x4  __attribute__((ext_vector_type(4)));

__device__ __forceinline__ void gload_lds16(const void* g, void* l) {
  __builtin_amdgcn_global_load_lds(
      (const __attribute__((address_space(1))) void*)g,
      (__attribute__((address_space(3))) void*)l, 16, 0, 0);
}

// Stage one 64x64 bf16 quarter-tile into LDS, granule-transposed:
// granule g in [0,512) holds (seg = g>>6, row = g&63) -> elem offset g*8.
// Thread t writes granule t (linear LDS dest, permuted global src).
__device__ __forceinline__ void stage_q(const __bf16* __restrict__ src, int ldk,
                                        __bf16* dstq, int t) {
  gload_lds16(src + (size_t)(t & 63) * ldk + ((t >> 6) << 3),
              dstq + (size_t)(t >> 6) * 512);
}

// ---------------- RMSNorm: fp32 row (H=2048) -> bf16 row ----------------
__global__ __launch_bounds__(256) void rmsnorm_kernel(
    const float* __restrict__ x, const float* __restrict__ w,
    __bf16* __restrict__ out) {
  constexpr int H = 2048;
  const int row = blockIdx.x;
  const int t = threadIdx.x;
  const float4* xr = (const float4*)(x + (size_t)row * H);
  float4 a = xr[t * 2 + 0];
  float4 b = xr[t * 2 + 1];
  float ss = a.x*a.x + a.y*a.y + a.z*a.z + a.w*a.w
           + b.x*b.x + b.y*b.y + b.z*b.z + b.w*b.w;
#pragma unroll
  for (int o = 32; o > 0; o >>= 1) ss += __shfl_xor(ss, o);
  __shared__ float red[4];
  if ((t & 63) == 0) red[t >> 6] = ss;
  __syncthreads();
  float tot = red[0] + red[1] + red[2] + red[3];
  float r = rsqrtf(tot * (1.0f / H) + 1e-6f);
  const float4* wr4 = (const float4*)w;
  float4 wa = wr4[t * 2 + 0];
  float4 wb = wr4[t * 2 + 1];
  bf16x8 ov;
  ov[0] = (__bf16)(a.x * wa.x * r);
  ov[1] = (__bf16)(a.y * wa.y * r);
  ov[2] = (__bf16)(a.z * wa.z * r);
  ov[3] = (__bf16)(a.w * wa.w * r);
  ov[4] = (__bf16)(b.x * wb.x * r);
  ov[5] = (__bf16)(b.y * wb.y * r);
  ov[6] = (__bf16)(b.z * wb.z * r);
  ov[7] = (__bf16)(b.w * wb.w * r);
  *(bf16x8*)(out + (size_t)row * H + (size_t)t * 8) = ov;
}

// ---------------- AWQ dequant -> transposed bf16 weight (N x K) ----------------
// GU=1: gate/up 16-col interleave: n<8192 -> row (n>>4)*32+(n&15); else +16.
template <int GU>
__global__ __launch_bounds__(256) void dequant_t_kernel(
    const int* __restrict__ qw, const int* __restrict__ qz,
    const float* __restrict__ sc, __bf16* __restrict__ wt,
    int K, int Cp, int Nfull) {
  const int t = threadIdx.x;
  const int k0 = blockIdx.x * 128 + (t & 63) * 2;
  const int c0 = blockIdx.y * 64 + (t >> 6) * 16;
  const int g = k0 >> 7;  // GROUP_SIZE = 128
  const uint32_t* qw0 = (const uint32_t*)qw + (size_t)k0 * Cp + c0;
  const uint32_t* qw1 = qw0 + Cp;
  const uint32_t* qzr = (const uint32_t*)qz + (size_t)g * Cp + c0;
  const float* scr = sc + (size_t)g * Nfull + (size_t)c0 * 8;

  uint32_t u0[16], u1[16], z[16];
#pragma unroll
  for (int j = 0; j < 4; j++) {
    *(int4*)(&u0[j*4]) = *(const int4*)(qw0 + j*4);
    *(int4*)(&u1[j*4]) = *(const int4*)(qw1 + j*4);
    *(int4*)(&z[j*4])  = *(const int4*)(qzr + j*4);
  }

#pragma unroll
  for (int i = 0; i < 16; i++) {
#pragma unroll
    for (int s = 0; s < 8; s++) {
      const int sh = ((s >> 1) * 4) + ((s & 1) ? 16 : 0);  // {0,16,4,20,8,24,12,28}
      const float zf = (float)((z[i] >> sh) & 15u);
      const float scv = scr[i * 8 + s];
      const float w0 = ((float)((u0[i] >> sh) & 15u) - zf) * scv;
      const float w1 = ((float)((u1[i] >> sh) & 15u) - zf) * scv;
      const int n = (c0 + i) * 8 + s;
      int row;
      if (GU) row = (n < 8192) ? ((n >> 4) * 32 + (n & 15))
                               : (((n - 8192) >> 4) * 32 + 16 + (n & 15));
      else    row = n;
      bf16x2 pv = {(__bf16)w0, (__bf16)w1};
      *(bf16x2*)(wt + (size_t)row * K + k0) = pv;
    }
  }
}

// ---------------- deep-pipelined 256xBN bf16 GEMM (B transposed: [N][K]) ------
// 512 threads, 8 waves (2Mx4N). BK=64, 4 phases/K-tile, m201-style schedule:
//   ph0: stage A-odd(t+1) -> other dbuf      (A-odd regions dead since ph3 of t-1)
//   ph1: stage B q0,q1(t+2) -> same dbuf     (B dead after ph0 reads)
//   ph2: BN256: B q2,q3(t+2); BN128: A-even(t+2)   (A-even dead after ph1)
//   ph3: BN256: A-even(t+2)
//   end of tile: vmcnt(6/4) -> drains all of tile t+1, leaves t+2 in flight.
// EPI 0: bf16 C = A@B^T   EPI 1: f32 C = addend + A@B^T
// EPI 2: bf16 act[row*8192+col] = silu(gate)*up with gate/up-interleaved B.
template <int BN, int EPI>
__global__ __launch_bounds__(512, 2) void gemm8p_kernel(
    const __bf16* __restrict__ A, const __bf16* __restrict__ Bt,
    void* __restrict__ Cv, const float* __restrict__ addend,
    int M, int N, int K) {
  constexpr int BQ = BN / 64;          // B quarters per K-tile (4 or 2)
  constexpr int NSTRIP = BN / 4;       // cols per wave (64 or 32)
  constexpr int NI = NSTRIP / 16;      // 4 or 2

  __shared__ __bf16 As[2][4][4096];    // [dbuf][quarter][granule*8]
  __shared__ __bf16 Bs[2][BQ][4096];

  const int t = threadIdx.x;
  const int w = t >> 6, l = t & 63;
  const int lm = l & 15, kb = l >> 4;
  const int wm = w >> 2, wn = w & 3;

  // XCD swizzle + grouped (16m x 8n) rasterization
  const int nwg = gridDim.x;
  const int bid = blockIdx.x;
  const int swz = (bid & 7) * (nwg >> 3) + (bid >> 3);
  const int nbm = M >> 8;
  const int per_g = nbm * 8;
  const int grp = swz / per_g, v = swz % per_g;
  const int bm0 = (v % nbm) * 256;
  const int bn0 = (grp * 8 + v / nbm) * BN;

  const __bf16* Ab = A + (size_t)bm0 * K;
  const __bf16* Bb = Bt + (size_t)bn0 * K;
  const int NT = K >> 6;

  // ---- prologue: tile 0 full + tile 1 {B all, A-even} ----
#pragma unroll
  for (int qa = 0; qa < 4; ++qa) stage_q(Ab + (size_t)(qa * 64) * K, K, &As[0][qa][0], t);
#pragma unroll
  for (int qb = 0; qb < BQ; ++qb) stage_q(Bb + (size_t)(qb * 64) * K, K, &Bs[0][qb][0], t);
#pragma unroll
  for (int qb = 0; qb < BQ; ++qb) stage_q(Bb + (size_t)(qb * 64) * K + 64, K, &Bs[1][qb][0], t);
  stage_q(Ab + 64, K, &As[1][0][0], t);
  stage_q(Ab + (size_t)128 * K + 64, K, &As[1][2][0], t);
  if (BN == 256) asm volatile("s_waitcnt vmcnt(6)" ::: "memory");
  else           asm volatile("s_waitcnt vmcnt(4)" ::: "memory");
  __builtin_amdgcn_s_barrier();

  f32x4 acc[8][NI] = {};
  bf16x8 bfr[NI][2];

  for (int kt = 0; kt < NT; ++kt) {
    const int d = kt & 1;
    const __bf16* A1 = Ab + (size_t)(kt + 1) * 64;
    const __bf16* A2 = Ab + (size_t)(kt + 2) * 64;
    const __bf16* B2 = Bb + (size_t)(kt + 2) * 64;
#pragma unroll
    for (int q = 0; q < 4; ++q) {
      // fragment ds_reads for this phase (phases 0-1: even A-quarter, 2-3: odd)
      bf16x8 af[2][2];
#pragma unroll
      for (int m2 = 0; m2 < 2; ++m2) {
        const int mi = q * 2 + m2;
        const int qa = wm * 2 + (mi >> 2);
        const int rq = (mi & 3) * 16 + lm;
#pragma unroll
        for (int kk = 0; kk < 2; ++kk)
          af[m2][kk] = *(const bf16x8*)&As[d][qa][(((kk * 4 + kb) << 6) + rq) << 3];
      }
      if (q == 0) {
#pragma unroll
        for (int ni = 0; ni < NI; ++ni) {
          const int nl = wn * NSTRIP + ni * 16 + lm;
#pragma unroll
          for (int kk = 0; kk < 2; ++kk)
            bfr[ni][kk] = *(const bf16x8*)&Bs[d][nl >> 6][(((kk * 4 + kb) << 6) + (nl & 63)) << 3];
        }
      }
      // staging (issued before this phase's first barrier)
      if (q == 0 && kt + 1 < NT) {
        stage_q(A1 + (size_t)64 * K,  K, &As[d ^ 1][1][0], t);
        stage_q(A1 + (size_t)192 * K, K, &As[d ^ 1][3][0], t);
      }
      if (q == 1 && kt + 2 < NT) {
        stage_q(B2,                  K, &Bs[d][0][0], t);
        stage_q(B2 + (size_t)64 * K, K, &Bs[d][1][0], t);
      }
      if (q == 2 && kt + 2 < NT) {
        if (BN == 256) {
          stage_q(B2 + (size_t)128 * K, K, &Bs[d][2][0], t);
          stage_q(B2 + (size_t)192 * K, K, &Bs[d][3][0], t);
        } else {
          stage_q(A2,                  K, &As[d][0][0], t);
          stage_q(A2 + (size_t)128 * K, K, &As[d][2][0], t);
        }
      }
      if (BN == 256 && q == 3 && kt + 2 < NT) {
        stage_q(A2,                  K, &As[d][0][0], t);
        stage_q(A2 + (size_t)128 * K, K, &As[d][2][0], t);
      }

      __builtin_amdgcn_s_barrier();
      __builtin_amdgcn_s_setprio(1);
#pragma unroll
      for (int m2 = 0; m2 < 2; ++m2)
#pragma unroll
        for (int ni = 0; ni < NI; ++ni)
#pragma unroll
          for (int kk = 0; kk < 2; ++kk)
            acc[q * 2 + m2][ni] = __builtin_amdgcn_mfma_f32_16x16x32_bf16(
                af[m2][kk], bfr[ni][kk], acc[q * 2 + m2][ni], 0, 0, 0);
      __builtin_amdgcn_s_setprio(0);
      if (q == 3) {
        if (kt + 2 < NT) {
          if (BN == 256) asm volatile("s_waitcnt vmcnt(6)" ::: "memory");
          else           asm volatile("s_waitcnt vmcnt(4)" ::: "memory");
        } else {
          asm volatile("s_waitcnt vmcnt(0)" ::: "memory");
        }
      }
      __builtin_amdgcn_s_barrier();
    }
  }

  // ---- epilogue ----
  const int crow0 = bm0 + wm * 128;
#pragma unroll
  for (int mi = 0; mi < 8; ++mi) {
    if (EPI == 2) {
#pragma unroll
      for (int p = 0; p < NI / 2; ++p) {
        const int ni = p * 2;
        const int col = ((bn0 + wn * 64 + ni * 16) >> 5) * 16 + lm;
#pragma unroll
        for (int r = 0; r < 4; ++r) {
          const int row = crow0 + mi * 16 + kb * 4 + r;
          const float gv = acc[mi][ni][r], uv = acc[mi][ni + 1][r];
          const float av = uv * (gv / (1.0f + __expf(-gv)));
          ((__bf16*)Cv)[(size_t)row * 8192 + col] = (__bf16)av;
        }
      }
    } else {
#pragma unroll
      for (int ni = 0; ni < NI; ++ni) {
        const int col = bn0 + wn * NSTRIP + ni * 16 + lm;
#pragma unroll
        for (int r = 0; r < 4; ++r) {
          const int row = crow0 + mi * 16 + kb * 4 + r;
          const size_t idx = (size_t)row * N + col;
          if (EPI == 0) ((__bf16*)Cv)[idx] = (__bf16)acc[mi][ni][r];
          else          ((float*)Cv)[idx] = addend[idx] + acc[mi][ni][r];
        }
      }
    }
  }
}

extern "C" void kernel_launch(void* const* d_in, const int* in_sizes, int n_in,
                              void* d_out, int out_size, void* d_ws, size_t ws_size,
                              hipStream_t stream) {
  const float* x      = (const float*)d_in[0];
  const float* ln1    = (const float*)d_in[1];
  const float* ln2    = (const float*)d_in[2];
  const int*   qkv_qw = (const int*)d_in[3];
  const int*   qkv_qz = (const int*)d_in[4];
  const float* qkv_sc = (const float*)d_in[5];
  const int*   o_qw   = (const int*)d_in[6];
  const int*   o_qz   = (const int*)d_in[7];
  const float* o_sc   = (const float*)d_in[8];
  const int*   gu_qw  = (const int*)d_in[9];
  const int*   gu_qz  = (const int*)d_in[10];
  const float* gu_sc  = (const float*)d_in[11];
  const int*   dn_qw  = (const int*)d_in[12];
  const int*   dn_qz  = (const int*)d_in[13];
  const float* dn_sc  = (const float*)d_in[14];

  constexpr int H = 2048, I = 8192, M = 4096;

  // Workspace layout (region reuse):
  char* ws = (char*)d_ws;
  __bf16* h   = (__bf16*)(ws + 0);                 // 16 MiB  [4096][2048]
  __bf16* q   = (__bf16*)(ws + 16777216ULL);       // 16 MiB  [4096][2048]
  float*  x2  = (float*)(ws + 33554432ULL);        // 32 MiB  [4096][2048] f32
  __bf16* W   = (__bf16*)(ws + 67108864ULL);       // 64 MiB  weight^T (reused)
  __bf16* act = (__bf16*)(ws + 134217728ULL);      // 64 MiB  [4096][8192]
  __bf16* Wdn = (__bf16*)(ws + 0);                 // 32 MiB  (h,q dead by then)

  // 1. h1 = rmsnorm(x, ln1)
  rmsnorm_kernel<<<dim3(M), dim3(256), 0, stream>>>(x, ln1, h);
  // 2. Wq^T (only first 2048 cols of qkv are used by the reference)
  dequant_t_kernel<0><<<dim3(16, 4), dim3(256), 0, stream>>>(qkv_qw, qkv_qz, qkv_sc, W, H, 768, 6144);
  // 3. q = h1 @ Wq
  gemm8p_kernel<128, 0><<<dim3(256), dim3(512), 0, stream>>>(h, W, (void*)q, nullptr, M, H, H);
  // 4. Wo^T
  dequant_t_kernel<0><<<dim3(16, 4), dim3(256), 0, stream>>>(o_qw, o_qz, o_sc, W, H, 256, 2048);
  // 5. x2 = x + q @ Wo
  gemm8p_kernel<128, 1><<<dim3(256), dim3(512), 0, stream>>>(q, W, (void*)x2, x, M, H, H);
  // 6. h2 = rmsnorm(x2, ln2)
  rmsnorm_kernel<<<dim3(M), dim3(256), 0, stream>>>(x2, ln2, h);
  // 7. Wgu^T [16384][2048], gate/up 16-col interleaved
  dequant_t_kernel<1><<<dim3(16, 32), dim3(256), 0, stream>>>(gu_qw, gu_qz, gu_sc, W, H, 2048, 16384);
  // 8. act = silu(gate)*up fused into GEMM epilogue
  gemm8p_kernel<256, 2><<<dim3(1024), dim3(512), 0, stream>>>(h, W, (void*)act, nullptr, M, 16384, H);
  // 9. Wdn^T [2048][8192]
  dequant_t_kernel<0><<<dim3(64, 4), dim3(256), 0, stream>>>(dn_qw, dn_qz, dn_sc, Wdn, I, 256, 2048);
  // 10. out = x2 + act @ Wdn
  gemm8p_kernel<128, 1><<<dim3(256), dim3(512), 0, stream>>>(act, Wdn, d_out, x2, M, H, I);
}

// Round 4
// 616.117 us; speedup vs baseline: 1.3562x; 1.3562x over previous
//
#include <hip/hip_runtime.h>
#include <hip/hip_bf16.h>
#include <stdint.h>

typedef __bf16 bf16x8 __attribute__((ext_vector_type(8)));
typedef __bf16 bf16x2 __attribute__((ext_vector_type(2)));
typedef float  f32x4  __attribute__((ext_vector_type(4)));

__device__ __forceinline__ void gload_lds16(const void* g, void* l) {
  __builtin_amdgcn_global_load_lds(
      (const __attribute__((address_space(1))) void*)g,
      (__attribute__((address_space(3))) void*)l, 16, 0, 0);
}

// Stage one 64x64 bf16 quarter-tile into LDS.
// LDS layout: row-major [64 rows][64 k] with granule-XOR swizzle:
//   logical (row r, 16B-granule gk) stored at byte r*128 + (gk^(r&7))*16.
// Thread t writes LDS linear granule t (byte t*16) = (r=t>>3, gsw=t&7),
// whose logical granule is gk = (t&7)^(r&7)  -> global src r*ldk + gk*8 elems.
// Per 8-lane group: 2 contiguous cache lines (line-optimal staging).
// stat = (t>>3)*K + (((t&7)^((t>>3)&7))<<3), dstoff = t*8 (elements).
__device__ __forceinline__ void stage_q(const __bf16* __restrict__ src, size_t stat,
                                        __bf16* dstq, int dstoff) {
  gload_lds16(src + stat, dstq + dstoff);
}

// ---------------- RMSNorm: fp32 row (H=2048) -> bf16 row ----------------
__global__ __launch_bounds__(256) void rmsnorm_kernel(
    const float* __restrict__ x, const float* __restrict__ w,
    __bf16* __restrict__ out) {
  constexpr int H = 2048;
  const int row = blockIdx.x;
  const int t = threadIdx.x;
  const float4* xr = (const float4*)(x + (size_t)row * H);
  float4 a = xr[t * 2 + 0];
  float4 b = xr[t * 2 + 1];
  float ss = a.x*a.x + a.y*a.y + a.z*a.z + a.w*a.w
           + b.x*b.x + b.y*b.y + b.z*b.z + b.w*b.w;
#pragma unroll
  for (int o = 32; o > 0; o >>= 1) ss += __shfl_xor(ss, o);
  __shared__ float red[4];
  if ((t & 63) == 0) red[t >> 6] = ss;
  __syncthreads();
  float tot = red[0] + red[1] + red[2] + red[3];
  float r = rsqrtf(tot * (1.0f / H) + 1e-6f);
  const float4* wr4 = (const float4*)w;
  float4 wa = wr4[t * 2 + 0];
  float4 wb = wr4[t * 2 + 1];
  bf16x8 ov;
  ov[0] = (__bf16)(a.x * wa.x * r);
  ov[1] = (__bf16)(a.y * wa.y * r);
  ov[2] = (__bf16)(a.z * wa.z * r);
  ov[3] = (__bf16)(a.w * wa.w * r);
  ov[4] = (__bf16)(b.x * wb.x * r);
  ov[5] = (__bf16)(b.y * wb.y * r);
  ov[6] = (__bf16)(b.z * wb.z * r);
  ov[7] = (__bf16)(b.w * wb.w * r);
  *(bf16x8*)(out + (size_t)row * H + (size_t)t * 8) = ov;
}

// ---------------- AWQ dequant -> transposed bf16 weight (N x K) ----------------
// GU=1: gate/up 16-col interleave: n<8192 -> row (n>>4)*32+(n&15); else +16.
template <int GU>
__global__ __launch_bounds__(256) void dequant_t_kernel(
    const int* __restrict__ qw, const int* __restrict__ qz,
    const float* __restrict__ sc, __bf16* __restrict__ wt,
    int K, int Cp, int Nfull) {
  const int t = threadIdx.x;
  const int k0 = blockIdx.x * 128 + (t & 63) * 2;
  const int c0 = blockIdx.y * 64 + (t >> 6) * 16;
  const int g = k0 >> 7;  // GROUP_SIZE = 128
  const uint32_t* qw0 = (const uint32_t*)qw + (size_t)k0 * Cp + c0;
  const uint32_t* qw1 = qw0 + Cp;
  const uint32_t* qzr = (const uint32_t*)qz + (size_t)g * Cp + c0;
  const float* scr = sc + (size_t)g * Nfull + (size_t)c0 * 8;

  uint32_t u0[16], u1[16], z[16];
#pragma unroll
  for (int j = 0; j < 4; j++) {
    *(int4*)(&u0[j*4]) = *(const int4*)(qw0 + j*4);
    *(int4*)(&u1[j*4]) = *(const int4*)(qw1 + j*4);
    *(int4*)(&z[j*4])  = *(const int4*)(qzr + j*4);
  }

#pragma unroll
  for (int i = 0; i < 16; i++) {
#pragma unroll
    for (int s = 0; s < 8; s++) {
      const int sh = ((s >> 1) * 4) + ((s & 1) ? 16 : 0);  // {0,16,4,20,8,24,12,28}
      const float zf = (float)((z[i] >> sh) & 15u);
      const float scv = scr[i * 8 + s];
      const float w0 = ((float)((u0[i] >> sh) & 15u) - zf) * scv;
      const float w1 = ((float)((u1[i] >> sh) & 15u) - zf) * scv;
      const int n = (c0 + i) * 8 + s;
      int row;
      if (GU) row = (n < 8192) ? ((n >> 4) * 32 + (n & 15))
                               : (((n - 8192) >> 4) * 32 + 16 + (n & 15));
      else    row = n;
      bf16x2 pv = {(__bf16)w0, (__bf16)w1};
      *(bf16x2*)(wt + (size_t)row * K + k0) = pv;
    }
  }
}

// ---------------- deep-pipelined 256xBN bf16 GEMM (B transposed: [N][K]) ------
// 512 threads, 8 waves (2Mx4N). BK=64, 4 phases/K-tile:
//   ph0: stage A-odd(t+1) -> other dbuf      ph1: stage B q0,q1(t+2) -> same dbuf
//   ph2: BN256: B q2,q3(t+2); BN128: A-even(t+2)   ph3(BN256): A-even(t+2)
//   tile end: vmcnt(6/4) drains tile t+1 fully, leaves t+2's loads in flight.
// LDS quarters: row-major with granule-XOR swizzle (see stage_q). ds_reads are
// bank-conflict-free; staging is cache-line contiguous.
// EPI 0: bf16 C = A@B^T   EPI 1: f32 C = addend + A@B^T
// EPI 2: bf16 act[row*8192+col] = silu(gate)*up with gate/up-interleaved B.
template <int BN, int EPI>
__global__ __launch_bounds__(512, 2) void gemm8p_kernel(
    const __bf16* __restrict__ A, const __bf16* __restrict__ Bt,
    void* __restrict__ Cv, const float* __restrict__ addend,
    int M, int N, int K) {
  constexpr int BQ = BN / 64;          // B quarters per K-tile (4 or 2)
  constexpr int NSTRIP = BN / 4;       // cols per wave (64 or 32)
  constexpr int NI = NSTRIP / 16;      // 4 or 2

  __shared__ __bf16 As[2][4][4096];    // [dbuf][quarter][swizzled row-major]
  __shared__ __bf16 Bs[2][BQ][4096];

  const int t = threadIdx.x;
  const int w = t >> 6, l = t & 63;
  const int lm = l & 15, kb = l >> 4;
  const int l7 = lm & 7;
  const int wm = w >> 2, wn = w & 3;

  const size_t stat = (size_t)(t >> 3) * K + (size_t)(((t & 7) ^ ((t >> 3) & 7)) << 3);
  const int dstoff = t * 8;

  // XCD swizzle + grouped (16m x 8n) rasterization
  const int nwg = gridDim.x;
  const int bid = blockIdx.x;
  const int swz = (bid & 7) * (nwg >> 3) + (bid >> 3);
  const int nbm = M >> 8;
  const int per_g = nbm * 8;
  const int grp = swz / per_g, v = swz % per_g;
  const int bm0 = (v % nbm) * 256;
  const int bn0 = (grp * 8 + v / nbm) * BN;

  const __bf16* Ab = A + (size_t)bm0 * K;
  const __bf16* Bb = Bt + (size_t)bn0 * K;
  const int NT = K >> 6;

  // ---- prologue: tile 0 full + tile 1 {B all, A q0,q2} ----
#pragma unroll
  for (int qa = 0; qa < 4; ++qa) stage_q(Ab + (size_t)(qa * 64) * K, stat, &As[0][qa][0], dstoff);
#pragma unroll
  for (int qb = 0; qb < BQ; ++qb) stage_q(Bb + (size_t)(qb * 64) * K, stat, &Bs[0][qb][0], dstoff);
#pragma unroll
  for (int qb = 0; qb < BQ; ++qb) stage_q(Bb + (size_t)(qb * 64) * K + 64, stat, &Bs[1][qb][0], dstoff);
  stage_q(Ab + 64, stat, &As[1][0][0], dstoff);
  stage_q(Ab + (size_t)128 * K + 64, stat, &As[1][2][0], dstoff);
  if (BN == 256) asm volatile("s_waitcnt vmcnt(6)" ::: "memory");
  else           asm volatile("s_waitcnt vmcnt(4)" ::: "memory");
  __builtin_amdgcn_s_barrier();

  f32x4 acc[8][NI] = {};
  bf16x8 bfr[NI][2];

  for (int kt = 0; kt < NT; ++kt) {
    const int d = kt & 1;
    const __bf16* A1 = Ab + (size_t)(kt + 1) * 64;
    const __bf16* A2 = Ab + (size_t)(kt + 2) * 64;
    const __bf16* B2 = Bb + (size_t)(kt + 2) * 64;
#pragma unroll
    for (int q = 0; q < 4; ++q) {
      // fragment ds_reads for this phase (phases 0-1: even A-quarter, 2-3: odd)
      bf16x8 af[2][2];
#pragma unroll
      for (int m2 = 0; m2 < 2; ++m2) {
        const int mi = q * 2 + m2;
        const int qa = wm * 2 + (mi >> 2);
        const int rq = (mi & 3) * 16 + lm;
#pragma unroll
        for (int kk = 0; kk < 2; ++kk)
          af[m2][kk] = *(const bf16x8*)
              &As[d][qa][(rq << 6) + ((((kk << 2) + kb) ^ l7) << 3)];
      }
      if (q == 0) {
#pragma unroll
        for (int ni = 0; ni < NI; ++ni) {
          const int nl = wn * NSTRIP + ni * 16 + lm;
#pragma unroll
          for (int kk = 0; kk < 2; ++kk)
            bfr[ni][kk] = *(const bf16x8*)
                &Bs[d][nl >> 6][((nl & 63) << 6) + ((((kk << 2) + kb) ^ l7) << 3)];
        }
      }
      // staging (issued before this phase's first barrier)
      if (q == 0 && kt + 1 < NT) {
        stage_q(A1 + (size_t)64 * K,  stat, &As[d ^ 1][1][0], dstoff);
        stage_q(A1 + (size_t)192 * K, stat, &As[d ^ 1][3][0], dstoff);
      }
      if (q == 1 && kt + 2 < NT) {
        stage_q(B2,                  stat, &Bs[d][0][0], dstoff);
        stage_q(B2 + (size_t)64 * K, stat, &Bs[d][1][0], dstoff);
      }
      if (q == 2 && kt + 2 < NT) {
        if (BN == 256) {
          stage_q(B2 + (size_t)128 * K, stat, &Bs[d][2][0], dstoff);
          stage_q(B2 + (size_t)192 * K, stat, &Bs[d][3][0], dstoff);
        } else {
          stage_q(A2,                  stat, &As[d][0][0], dstoff);
          stage_q(A2 + (size_t)128 * K, stat, &As[d][2][0], dstoff);
        }
      }
      if (BN == 256 && q == 3 && kt + 2 < NT) {
        stage_q(A2,                  stat, &As[d][0][0], dstoff);
        stage_q(A2 + (size_t)128 * K, stat, &As[d][2][0], dstoff);
      }

      __builtin_amdgcn_s_barrier();
      __builtin_amdgcn_s_setprio(1);
#pragma unroll
      for (int m2 = 0; m2 < 2; ++m2)
#pragma unroll
        for (int ni = 0; ni < NI; ++ni)
#pragma unroll
          for (int kk = 0; kk < 2; ++kk)
            acc[q * 2 + m2][ni] = __builtin_amdgcn_mfma_f32_16x16x32_bf16(
                af[m2][kk], bfr[ni][kk], acc[q * 2 + m2][ni], 0, 0, 0);
      __builtin_amdgcn_s_setprio(0);
      if (q == 3) {
        if (kt + 2 < NT) {
          if (BN == 256) asm volatile("s_waitcnt vmcnt(6)" ::: "memory");
          else           asm volatile("s_waitcnt vmcnt(4)" ::: "memory");
        } else {
          asm volatile("s_waitcnt vmcnt(0)" ::: "memory");
        }
      }
      __builtin_amdgcn_s_barrier();
    }
  }

  // ---- epilogue ----
  const int crow0 = bm0 + wm * 128;
#pragma unroll
  for (int mi = 0; mi < 8; ++mi) {
    if (EPI == 2) {
#pragma unroll
      for (int p = 0; p < NI / 2; ++p) {
        const int ni = p * 2;
        const int col = ((bn0 + wn * 64 + ni * 16) >> 5) * 16 + lm;
#pragma unroll
        for (int r = 0; r < 4; ++r) {
          const int row = crow0 + mi * 16 + kb * 4 + r;
          const float gv = acc[mi][ni][r], uv = acc[mi][ni + 1][r];
          const float av = uv * (gv / (1.0f + __expf(-gv)));
          ((__bf16*)Cv)[(size_t)row * 8192 + col] = (__bf16)av;
        }
      }
    } else {
#pragma unroll
      for (int ni = 0; ni < NI; ++ni) {
        const int col = bn0 + wn * NSTRIP + ni * 16 + lm;
#pragma unroll
        for (int r = 0; r < 4; ++r) {
          const int row = crow0 + mi * 16 + kb * 4 + r;
          const size_t idx = (size_t)row * N + col;
          if (EPI == 0) ((__bf16*)Cv)[idx] = (__bf16)acc[mi][ni][r];
          else          ((float*)Cv)[idx] = addend[idx] + acc[mi][ni][r];
        }
      }
    }
  }
}

extern "C" void kernel_launch(void* const* d_in, const int* in_sizes, int n_in,
                              void* d_out, int out_size, void* d_ws, size_t ws_size,
                              hipStream_t stream) {
  const float* x      = (const float*)d_in[0];
  const float* ln1    = (const float*)d_in[1];
  const float* ln2    = (const float*)d_in[2];
  const int*   qkv_qw = (const int*)d_in[3];
  const int*   qkv_qz = (const int*)d_in[4];
  const float* qkv_sc = (const float*)d_in[5];
  const int*   o_qw   = (const int*)d_in[6];
  const int*   o_qz   = (const int*)d_in[7];
  const float* o_sc   = (const float*)d_in[8];
  const int*   gu_qw  = (const int*)d_in[9];
  const int*   gu_qz  = (const int*)d_in[10];
  const float* gu_sc  = (const float*)d_in[11];
  const int*   dn_qw  = (const int*)d_in[12];
  const int*   dn_qz  = (const int*)d_in[13];
  const float* dn_sc  = (const float*)d_in[14];

  constexpr int H = 2048, I = 8192, M = 4096;

  // Workspace layout (region reuse):
  char* ws = (char*)d_ws;
  __bf16* h   = (__bf16*)(ws + 0);                 // 16 MiB  [4096][2048]
  __bf16* q   = (__bf16*)(ws + 16777216ULL);       // 16 MiB  [4096][2048]
  float*  x2  = (float*)(ws + 33554432ULL);        // 32 MiB  [4096][2048] f32
  __bf16* W   = (__bf16*)(ws + 67108864ULL);       // 64 MiB  weight^T (reused)
  __bf16* act = (__bf16*)(ws + 134217728ULL);      // 64 MiB  [4096][8192]
  __bf16* Wdn = (__bf16*)(ws + 0);                 // 32 MiB  (h,q dead by then)

  // 1. h1 = rmsnorm(x, ln1)
  rmsnorm_kernel<<<dim3(M), dim3(256), 0, stream>>>(x, ln1, h);
  // 2. Wq^T (only first 2048 cols of qkv are used by the reference)
  dequant_t_kernel<0><<<dim3(16, 4), dim3(256), 0, stream>>>(qkv_qw, qkv_qz, qkv_sc, W, H, 768, 6144);
  // 3. q = h1 @ Wq
  gemm8p_kernel<128, 0><<<dim3(256), dim3(512), 0, stream>>>(h, W, (void*)q, nullptr, M, H, H);
  // 4. Wo^T
  dequant_t_kernel<0><<<dim3(16, 4), dim3(256), 0, stream>>>(o_qw, o_qz, o_sc, W, H, 256, 2048);
  // 5. x2 = x + q @ Wo
  gemm8p_kernel<128, 1><<<dim3(256), dim3(512), 0, stream>>>(q, W, (void*)x2, x, M, H, H);
  // 6. h2 = rmsnorm(x2, ln2)
  rmsnorm_kernel<<<dim3(M), dim3(256), 0, stream>>>(x2, ln2, h);
  // 7. Wgu^T [16384][2048], gate/up 16-col interleaved
  dequant_t_kernel<1><<<dim3(16, 32), dim3(256), 0, stream>>>(gu_qw, gu_qz, gu_sc, W, H, 2048, 16384);
  // 8. act = silu(gate)*up fused into GEMM epilogue
  gemm8p_kernel<256, 2><<<dim3(1024), dim3(512), 0, stream>>>(h, W, (void*)act, nullptr, M, 16384, H);
  // 9. Wdn^T [2048][8192]
  dequant_t_kernel<0><<<dim3(64, 4), dim3(256), 0, stream>>>(dn_qw, dn_qz, dn_sc, Wdn, I, 256, 2048);
  // 10. out = x2 + act @ Wdn
  gemm8p_kernel<128, 1><<<dim3(256), dim3(512), 0, stream>>>(act, Wdn, d_out, x2, M, H, I);
}

// Round 5
// 556.217 us; speedup vs baseline: 1.5022x; 1.1077x over previous
//
#include <hip/hip_runtime.h>
#include <hip/hip_bf16.h>
#include <stdint.h>

typedef __bf16 bf16x8 __attribute__((ext_vector_type(8)));
typedef __bf16 bf16x2 __attribute__((ext_vector_type(2)));
typedef float  f32x4  __attribute__((ext_vector_type(4)));

template <int V> struct ic { static constexpr int value = V; };

__device__ __forceinline__ void gload_lds16(const void* g, void* l) {
  __builtin_amdgcn_global_load_lds(
      (const __attribute__((address_space(1))) void*)g,
      (__attribute__((address_space(3))) void*)l, 16, 0, 0);
}

// ---------------- RMSNorm: fp32 row (H=2048) -> bf16 row ----------------
__global__ __launch_bounds__(256) void rmsnorm_kernel(
    const float* __restrict__ x, const float* __restrict__ w,
    __bf16* __restrict__ out) {
  constexpr int H = 2048;
  const int row = blockIdx.x;
  const int t = threadIdx.x;
  const float4* xr = (const float4*)(x + (size_t)row * H);
  float4 a = xr[t * 2 + 0];
  float4 b = xr[t * 2 + 1];
  float ss = a.x*a.x + a.y*a.y + a.z*a.z + a.w*a.w
           + b.x*b.x + b.y*b.y + b.z*b.z + b.w*b.w;
#pragma unroll
  for (int o = 32; o > 0; o >>= 1) ss += __shfl_xor(ss, o);
  __shared__ float red[4];
  if ((t & 63) == 0) red[t >> 6] = ss;
  __syncthreads();
  float tot = red[0] + red[1] + red[2] + red[3];
  float r = rsqrtf(tot * (1.0f / H) + 1e-6f);
  const float4* wr4 = (const float4*)w;
  float4 wa = wr4[t * 2 + 0];
  float4 wb = wr4[t * 2 + 1];
  bf16x8 ov;
  ov[0] = (__bf16)(a.x * wa.x * r);
  ov[1] = (__bf16)(a.y * wa.y * r);
  ov[2] = (__bf16)(a.z * wa.z * r);
  ov[3] = (__bf16)(a.w * wa.w * r);
  ov[4] = (__bf16)(b.x * wb.x * r);
  ov[5] = (__bf16)(b.y * wb.y * r);
  ov[6] = (__bf16)(b.z * wb.z * r);
  ov[7] = (__bf16)(b.w * wb.w * r);
  *(bf16x8*)(out + (size_t)row * H + (size_t)t * 8) = ov;
}

// ---------------- AWQ dequant -> transposed bf16 weight (N x K) ----------------
// GU=1: gate/up 16-col interleave: n<8192 -> row (n>>4)*32+(n&15); else +16.
template <int GU>
__global__ __launch_bounds__(256) void dequant_t_kernel(
    const int* __restrict__ qw, const int* __restrict__ qz,
    const float* __restrict__ sc, __bf16* __restrict__ wt,
    int K, int Cp, int Nfull) {
  const int t = threadIdx.x;
  const int k0 = blockIdx.x * 128 + (t & 63) * 2;
  const int c0 = blockIdx.y * 64 + (t >> 6) * 16;
  const int g = k0 >> 7;  // GROUP_SIZE = 128
  const uint32_t* qw0 = (const uint32_t*)qw + (size_t)k0 * Cp + c0;
  const uint32_t* qw1 = qw0 + Cp;
  const uint32_t* qzr = (const uint32_t*)qz + (size_t)g * Cp + c0;
  const float* scr = sc + (size_t)g * Nfull + (size_t)c0 * 8;

  uint32_t u0[16], u1[16], z[16];
#pragma unroll
  for (int j = 0; j < 4; j++) {
    *(int4*)(&u0[j*4]) = *(const int4*)(qw0 + j*4);
    *(int4*)(&u1[j*4]) = *(const int4*)(qw1 + j*4);
    *(int4*)(&z[j*4])  = *(const int4*)(qzr + j*4);
  }

#pragma unroll
  for (int i = 0; i < 16; i++) {
#pragma unroll
    for (int s = 0; s < 8; s++) {
      const int sh = ((s >> 1) * 4) + ((s & 1) ? 16 : 0);  // {0,16,4,20,8,24,12,28}
      const float zf = (float)((z[i] >> sh) & 15u);
      const float scv = scr[i * 8 + s];
      const float w0 = ((float)((u0[i] >> sh) & 15u) - zf) * scv;
      const float w1 = ((float)((u1[i] >> sh) & 15u) - zf) * scv;
      const int n = (c0 + i) * 8 + s;
      int row;
      if (GU) row = (n < 8192) ? ((n >> 4) * 32 + (n & 15))
                               : (((n - 8192) >> 4) * 32 + 16 + (n & 15));
      else    row = n;
      bf16x2 pv = {(__bf16)w0, (__bf16)w1};
      *(bf16x2*)(wt + (size_t)row * K + k0) = pv;
    }
  }
}

// ---------------- deep-pipelined 256xBN bf16 GEMM (B transposed: [N][K]) ------
// Same schedule/layout as r4 (verified), but: K compile-time, kt-loop unrolled
// by 2 (dbuf index d compile-time -> all ds_read addrs = base VGPR + imm),
// staging via 8 stream pointers (+128B/tile), last 2 tiles peeled (no branches
// in steady state), MFMA cluster kk-outer (8 independent chains).
template <int BN, int EPI, int KC>
__global__ __launch_bounds__(512, 2) void gemm8p_kernel(
    const __bf16* __restrict__ A, const __bf16* __restrict__ Bt,
    void* __restrict__ Cv, const float* __restrict__ addend,
    int M, int N) {
  constexpr int NT = KC / 64;
  constexpr int BQ = BN / 64;          // B quarters per K-tile (4 or 2)
  constexpr int NSTRIP = BN / 4;       // cols per wave (64 or 32)
  constexpr int NI = NSTRIP / 16;      // 4 or 2

  __shared__ alignas(16) __bf16 As[8 * 4096];        // [d*4+qa][row64][gran8][8]
  __shared__ alignas(16) __bf16 Bs[2 * BQ * 4096];

  const int t = threadIdx.x;
  const int w = t >> 6, l = t & 63;
  const int lm = l & 15, kb = l >> 4;
  const int l7 = lm & 7;
  const int wm = w >> 2, wn = w & 3;

  const size_t stat = (size_t)(t >> 3) * KC + (size_t)(((t & 7) ^ ((t >> 3) & 7)) << 3);

  // XCD swizzle + grouped (16m x 8n) rasterization
  const int nwg = gridDim.x;
  const int bid = blockIdx.x;
  const int swz = (bid & 7) * (nwg >> 3) + (bid >> 3);
  const int nbm = M >> 8;
  const int per_g = nbm * 8;
  const int grp = swz / per_g, v = swz % per_g;
  const int bm0 = (v % nbm) * 256;
  const int bn0 = (grp * 8 + v / nbm) * BN;

  const __bf16* Ab = A + (size_t)bm0 * KC;
  const __bf16* Bb = Bt + (size_t)bn0 * KC;

  // LDS read byte-offset bases (per-thread VGPRs; everything else is imm)
  const uint32_t gsw0 = (uint32_t)((kb ^ l7) << 4);
  const uint32_t gsw1 = (uint32_t)(((4 + kb) ^ l7) << 4);
  const uint32_t arow = (uint32_t)(wm * 16384 + lm * 128);
  const uint32_t aoff0 = arow + gsw0, aoff1 = arow + gsw1;
  const uint32_t brow = (BN == 256)
      ? (uint32_t)(wn * 8192 + lm * 128)
      : (uint32_t)((wn >> 1) * 8192 + (wn & 1) * 4096 + lm * 128);
  const uint32_t boff0 = brow + gsw0, boff1 = brow + gsw1;
  const char* AsC = (const char*)As;
  const char* BsC = (const char*)Bs;

  // ---- prologue: tile0 full + tile1 {B all, A q0,q2} ----
#pragma unroll
  for (int qa = 0; qa < 4; ++qa)
    gload_lds16(Ab + stat + (size_t)(qa * 64) * KC, As + qa * 4096 + t * 8);
#pragma unroll
  for (int qb = 0; qb < BQ; ++qb)
    gload_lds16(Bb + stat + (size_t)(qb * 64) * KC, Bs + qb * 4096 + t * 8);
#pragma unroll
  for (int qb = 0; qb < BQ; ++qb)
    gload_lds16(Bb + stat + (size_t)(qb * 64) * KC + 64, Bs + (BQ + qb) * 4096 + t * 8);
  gload_lds16(Ab + stat + 64, As + 4 * 4096 + t * 8);
  gload_lds16(Ab + stat + (size_t)128 * KC + 64, As + 6 * 4096 + t * 8);
  if (BN == 256) asm volatile("s_waitcnt vmcnt(6)" ::: "memory");
  else           asm volatile("s_waitcnt vmcnt(4)" ::: "memory");
  __builtin_amdgcn_s_barrier();

  // stream pointers positioned at first steady-tile use (kt=0)
  const __bf16* pA0 = Ab + stat + 128;
  const __bf16* pA1 = Ab + stat + (size_t)64 * KC + 64;
  const __bf16* pA2 = Ab + stat + (size_t)128 * KC + 128;
  const __bf16* pA3 = Ab + stat + (size_t)192 * KC + 64;
  const __bf16* pB0 = Bb + stat + 128;
  const __bf16* pB1 = Bb + stat + (size_t)64 * KC + 128;
  const __bf16* pB2 = Bb + stat + (size_t)128 * KC + 128;  // BN256 only
  const __bf16* pB3 = Bb + stat + (size_t)192 * KC + 128;  // BN256 only

  f32x4 acc[8][NI] = {};
  bf16x8 bfr[NI][2];

  // STG: 2 = full staging, 1 = A(t+1)-odd only + vmcnt(0), 0 = none.
  auto tile = [&](auto Dc, auto Sc) {
    constexpr int D = decltype(Dc)::value;
    constexpr int STG = decltype(Sc)::value;
#pragma unroll
    for (int q = 0; q < 4; ++q) {
      bf16x8 af[2][2];
#pragma unroll
      for (int m2 = 0; m2 < 2; ++m2) {
        const int mi = q * 2 + m2;
        const uint32_t imA = (uint32_t)((D * 4 + (mi >> 2)) * 8192 + (mi & 3) * 2048);
        af[m2][0] = *(const bf16x8*)(AsC + aoff0 + imA);
        af[m2][1] = *(const bf16x8*)(AsC + aoff1 + imA);
      }
      if (q == 0) {
#pragma unroll
        for (int ni = 0; ni < NI; ++ni) {
          const uint32_t imB = (uint32_t)(D * BQ * 8192 + ni * 2048);
          bfr[ni][0] = *(const bf16x8*)(BsC + boff0 + imB);
          bfr[ni][1] = *(const bf16x8*)(BsC + boff1 + imB);
        }
      }
      if (STG >= 1 && q == 0) {
        gload_lds16(pA1, As + ((D ^ 1) * 4 + 1) * 4096 + t * 8);
        gload_lds16(pA3, As + ((D ^ 1) * 4 + 3) * 4096 + t * 8);
      }
      if (STG == 2) {
        if (q == 1) {
          gload_lds16(pB0, Bs + (D * BQ + 0) * 4096 + t * 8);
          gload_lds16(pB1, Bs + (D * BQ + 1) * 4096 + t * 8);
        }
        if (q == 2) {
          if (BN == 256) {
            gload_lds16(pB2, Bs + (D * BQ + 2) * 4096 + t * 8);
            gload_lds16(pB3, Bs + (D * BQ + 3) * 4096 + t * 8);
          } else {
            gload_lds16(pA0, As + (D * 4 + 0) * 4096 + t * 8);
            gload_lds16(pA2, As + (D * 4 + 2) * 4096 + t * 8);
          }
        }
        if (BN == 256 && q == 3) {
          gload_lds16(pA0, As + (D * 4 + 0) * 4096 + t * 8);
          gload_lds16(pA2, As + (D * 4 + 2) * 4096 + t * 8);
        }
      }
      __builtin_amdgcn_s_barrier();
      __builtin_amdgcn_s_setprio(1);
#pragma unroll
      for (int kk = 0; kk < 2; ++kk)
#pragma unroll
        for (int ni = 0; ni < NI; ++ni)
#pragma unroll
          for (int m2 = 0; m2 < 2; ++m2)
            acc[q * 2 + m2][ni] = __builtin_amdgcn_mfma_f32_16x16x32_bf16(
                af[m2][kk], bfr[ni][kk], acc[q * 2 + m2][ni], 0, 0, 0);
      __builtin_amdgcn_s_setprio(0);
      if (q == 3) {
        if (STG == 2) {
          if (BN == 256) asm volatile("s_waitcnt vmcnt(6)" ::: "memory");
          else           asm volatile("s_waitcnt vmcnt(4)" ::: "memory");
        } else if (STG == 1) {
          asm volatile("s_waitcnt vmcnt(0)" ::: "memory");
        }
      }
      __builtin_amdgcn_s_barrier();
    }
    if (STG == 2) {
      pA0 += 64; pA1 += 64; pA2 += 64; pA3 += 64;
      pB0 += 64; pB1 += 64;
      if (BN == 256) { pB2 += 64; pB3 += 64; }
    }
  };

#pragma unroll 1
  for (int it = 0; it < NT / 2 - 1; ++it) {
    tile(ic<0>{}, ic<2>{});
    tile(ic<1>{}, ic<2>{});
  }
  tile(ic<0>{}, ic<1>{});   // kt = NT-2: stage A(NT-1)-odd, then drain
  tile(ic<1>{}, ic<0>{});   // kt = NT-1: compute only

  // ---- epilogue ----
  const int crow0 = bm0 + wm * 128;
#pragma unroll
  for (int mi = 0; mi < 8; ++mi) {
    if (EPI == 2) {
#pragma unroll
      for (int p = 0; p < NI / 2; ++p) {
        const int ni = p * 2;
        const int col = ((bn0 + wn * 64 + ni * 16) >> 5) * 16 + lm;
#pragma unroll
        for (int r = 0; r < 4; ++r) {
          const int row = crow0 + mi * 16 + kb * 4 + r;
          const float gv = acc[mi][ni][r], uv = acc[mi][ni + 1][r];
          const float av = uv * (gv / (1.0f + __expf(-gv)));
          ((__bf16*)Cv)[(size_t)row * 8192 + col] = (__bf16)av;
        }
      }
    } else {
#pragma unroll
      for (int ni = 0; ni < NI; ++ni) {
        const int col = bn0 + wn * NSTRIP + ni * 16 + lm;
#pragma unroll
        for (int r = 0; r < 4; ++r) {
          const int row = crow0 + mi * 16 + kb * 4 + r;
          const size_t idx = (size_t)row * N + col;
          if (EPI == 0) ((__bf16*)Cv)[idx] = (__bf16)acc[mi][ni][r];
          else          ((float*)Cv)[idx] = addend[idx] + acc[mi][ni][r];
        }
      }
    }
  }
}

extern "C" void kernel_launch(void* const* d_in, const int* in_sizes, int n_in,
                              void* d_out, int out_size, void* d_ws, size_t ws_size,
                              hipStream_t stream) {
  const float* x      = (const float*)d_in[0];
  const float* ln1    = (const float*)d_in[1];
  const float* ln2    = (const float*)d_in[2];
  const int*   qkv_qw = (const int*)d_in[3];
  const int*   qkv_qz = (const int*)d_in[4];
  const float* qkv_sc = (const float*)d_in[5];
  const int*   o_qw   = (const int*)d_in[6];
  const int*   o_qz   = (const int*)d_in[7];
  const float* o_sc   = (const float*)d_in[8];
  const int*   gu_qw  = (const int*)d_in[9];
  const int*   gu_qz  = (const int*)d_in[10];
  const float* gu_sc  = (const float*)d_in[11];
  const int*   dn_qw  = (const int*)d_in[12];
  const int*   dn_qz  = (const int*)d_in[13];
  const float* dn_sc  = (const float*)d_in[14];

  constexpr int M = 4096;

  // Workspace layout (region reuse):
  char* ws = (char*)d_ws;
  __bf16* h   = (__bf16*)(ws + 0);                 // 16 MiB  [4096][2048]
  __bf16* q   = (__bf16*)(ws + 16777216ULL);       // 16 MiB  [4096][2048]
  float*  x2  = (float*)(ws + 33554432ULL);        // 32 MiB  [4096][2048] f32
  __bf16* W   = (__bf16*)(ws + 67108864ULL);       // 64 MiB  weight^T (reused)
  __bf16* act = (__bf16*)(ws + 134217728ULL);      // 64 MiB  [4096][8192]
  __bf16* Wdn = (__bf16*)(ws + 0);                 // 32 MiB  (h,q dead by then)

  // 1. h1 = rmsnorm(x, ln1)
  rmsnorm_kernel<<<dim3(M), dim3(256), 0, stream>>>(x, ln1, h);
  // 2. Wq^T (only first 2048 cols of qkv are used by the reference)
  dequant_t_kernel<0><<<dim3(16, 4), dim3(256), 0, stream>>>(qkv_qw, qkv_qz, qkv_sc, W, 2048, 768, 6144);
  // 3. q = h1 @ Wq
  gemm8p_kernel<128, 0, 2048><<<dim3(256), dim3(512), 0, stream>>>(h, W, (void*)q, nullptr, M, 2048);
  // 4. Wo^T
  dequant_t_kernel<0><<<dim3(16, 4), dim3(256), 0, stream>>>(o_qw, o_qz, o_sc, W, 2048, 256, 2048);
  // 5. x2 = x + q @ Wo
  gemm8p_kernel<128, 1, 2048><<<dim3(256), dim3(512), 0, stream>>>(q, W, (void*)x2, x, M, 2048);
  // 6. h2 = rmsnorm(x2, ln2)
  rmsnorm_kernel<<<dim3(M), dim3(256), 0, stream>>>(x2, ln2, h);
  // 7. Wgu^T [16384][2048], gate/up 16-col interleaved
  dequant_t_kernel<1><<<dim3(16, 32), dim3(256), 0, stream>>>(gu_qw, gu_qz, gu_sc, W, 2048, 2048, 16384);
  // 8. act = silu(gate)*up fused into GEMM epilogue
  gemm8p_kernel<256, 2, 2048><<<dim3(1024), dim3(512), 0, stream>>>(h, W, (void*)act, nullptr, M, 16384);
  // 9. Wdn^T [2048][8192]
  dequant_t_kernel<0><<<dim3(64, 4), dim3(256), 0, stream>>>(dn_qw, dn_qz, dn_sc, Wdn, 8192, 256, 2048);
  // 10. out = x2 + act @ Wdn
  gemm8p_kernel<128, 1, 8192><<<dim3(256), dim3(512), 0, stream>>>(act, Wdn, d_out, x2, M, 2048);
}

// Round 7
// 513.411 us; speedup vs baseline: 1.6275x; 1.0834x over previous
//
#include <hip/hip_runtime.h>
#include <hip/hip_bf16.h>
#include <stdint.h>

typedef __bf16 bf16x8 __attribute__((ext_vector_type(8)));
typedef __bf16 bf16x2 __attribute__((ext_vector_type(2)));
typedef float  f32x4  __attribute__((ext_vector_type(4)));

template <int V> struct ic { static constexpr int value = V; };

__device__ __forceinline__ void gload_lds16(const void* g, void* l) {
  __builtin_amdgcn_global_load_lds(
      (const __attribute__((address_space(1))) void*)g,
      (__attribute__((address_space(3))) void*)l, 16, 0, 0);
}

// ---------------- RMSNorm: fp32 row (H=2048) -> bf16 row ----------------
__global__ __launch_bounds__(256) void rmsnorm_kernel(
    const float* __restrict__ x, const float* __restrict__ w,
    __bf16* __restrict__ out) {
  constexpr int H = 2048;
  const int row = blockIdx.x;
  const int t = threadIdx.x;
  const float4* xr = (const float4*)(x + (size_t)row * H);
  float4 a = xr[t * 2 + 0];
  float4 b = xr[t * 2 + 1];
  float ss = a.x*a.x + a.y*a.y + a.z*a.z + a.w*a.w
           + b.x*b.x + b.y*b.y + b.z*b.z + b.w*b.w;
#pragma unroll
  for (int o = 32; o > 0; o >>= 1) ss += __shfl_xor(ss, o);
  __shared__ float red[4];
  if ((t & 63) == 0) red[t >> 6] = ss;
  __syncthreads();
  float tot = red[0] + red[1] + red[2] + red[3];
  float r = rsqrtf(tot * (1.0f / H) + 1e-6f);
  const float4* wr4 = (const float4*)w;
  float4 wa = wr4[t * 2 + 0];
  float4 wb = wr4[t * 2 + 1];
  bf16x8 ov;
  ov[0] = (__bf16)(a.x * wa.x * r);
  ov[1] = (__bf16)(a.y * wa.y * r);
  ov[2] = (__bf16)(a.z * wa.z * r);
  ov[3] = (__bf16)(a.w * wa.w * r);
  ov[4] = (__bf16)(b.x * wb.x * r);
  ov[5] = (__bf16)(b.y * wb.y * r);
  ov[6] = (__bf16)(b.z * wb.z * r);
  ov[7] = (__bf16)(b.w * wb.w * r);
  *(bf16x8*)(out + (size_t)row * H + (size_t)t * 8) = ov;
}

// ---------------- AWQ dequant -> transposed bf16 weight (N x K) ----------------
// GU=1: gate/up 16-col interleave: n<8192 -> row (n>>4)*32+(n&15); else +16.
template <int GU>
__global__ __launch_bounds__(256) void dequant_t_kernel(
    const int* __restrict__ qw, const int* __restrict__ qz,
    const float* __restrict__ sc, __bf16* __restrict__ wt,
    int K, int Cp, int Nfull) {
  const int t = threadIdx.x;
  const int k0 = blockIdx.x * 128 + (t & 63) * 2;
  const int c0 = blockIdx.y * 64 + (t >> 6) * 16;
  const int g = k0 >> 7;  // GROUP_SIZE = 128
  const uint32_t* qw0 = (const uint32_t*)qw + (size_t)k0 * Cp + c0;
  const uint32_t* qw1 = qw0 + Cp;
  const uint32_t* qzr = (const uint32_t*)qz + (size_t)g * Cp + c0;
  const float* scr = sc + (size_t)g * Nfull + (size_t)c0 * 8;

  uint32_t u0[16], u1[16], z[16];
#pragma unroll
  for (int j = 0; j < 4; j++) {
    *(int4*)(&u0[j*4]) = *(const int4*)(qw0 + j*4);
    *(int4*)(&u1[j*4]) = *(const int4*)(qw1 + j*4);
    *(int4*)(&z[j*4])  = *(const int4*)(qzr + j*4);
  }

#pragma unroll
  for (int i = 0; i < 16; i++) {
#pragma unroll
    for (int s = 0; s < 8; s++) {
      const int sh = ((s >> 1) * 4) + ((s & 1) ? 16 : 0);  // {0,16,4,20,8,24,12,28}
      const float zf = (float)((z[i] >> sh) & 15u);
      const float scv = scr[i * 8 + s];
      const float w0 = ((float)((u0[i] >> sh) & 15u) - zf) * scv;
      const float w1 = ((float)((u1[i] >> sh) & 15u) - zf) * scv;
      const int n = (c0 + i) * 8 + s;
      int row;
      if (GU) row = (n < 8192) ? ((n >> 4) * 32 + (n & 15))
                               : (((n - 8192) >> 4) * 32 + 16 + (n & 15));
      else    row = n;
      bf16x2 pv = {(__bf16)w0, (__bf16)w1};
      *(bf16x2*)(wt + (size_t)row * K + k0) = pv;
    }
  }
}

// ---------------- deep-pipelined 256xBN bf16 GEMM (B transposed: [N][K]) ------
// r6 structure with the bfr clobber fixed: BOTH af and bfr are double-buffered.
// Phase q issues ds_reads for phase q+1 (overlap with MFMA of phase q);
// ph3: lgkmcnt(0) + vmcnt(4) + barrier publishes tile t+1, then next-tile ph0
// fragments (af[0], bfr[D^1]) prefetch under MFMA-ph3 which consumes af[1],
// bfr[D].
template <int BN, int EPI, int KC>
__global__ __launch_bounds__(512, 2) void gemm8p_kernel(
    const __bf16* __restrict__ A, const __bf16* __restrict__ Bt,
    void* __restrict__ Cv, const float* __restrict__ addend,
    int M, int N) {
  constexpr int NT = KC / 64;
  constexpr int BQ = BN / 64;          // B quarters per K-tile (4 or 2)
  constexpr int NSTRIP = BN / 4;       // cols per wave (64 or 32)
  constexpr int NI = NSTRIP / 16;      // 4 or 2

  __shared__ alignas(16) __bf16 As[8 * 4096];        // [d*4+qa][row64][gran8][8]
  __shared__ alignas(16) __bf16 Bs[2 * BQ * 4096];

  const int t = threadIdx.x;
  const int w = t >> 6, l = t & 63;
  const int lm = l & 15, kb = l >> 4;
  const int l7 = lm & 7;
  const int wm = w >> 2, wn = w & 3;

  const size_t stat = (size_t)(t >> 3) * KC + (size_t)(((t & 7) ^ ((t >> 3) & 7)) << 3);

  // XCD swizzle + grouped (16m x 8n) rasterization
  const int nwg = gridDim.x;
  const int bid = blockIdx.x;
  const int swz = (bid & 7) * (nwg >> 3) + (bid >> 3);
  const int nbm = M >> 8;
  const int per_g = nbm * 8;
  const int grp = swz / per_g, v = swz % per_g;
  const int bm0 = (v % nbm) * 256;
  const int bn0 = (grp * 8 + v / nbm) * BN;

  const __bf16* Ab = A + (size_t)bm0 * KC;
  const __bf16* Bb = Bt + (size_t)bn0 * KC;

  // LDS read byte-offset bases (per-thread VGPRs; everything else is imm)
  const uint32_t gsw0 = (uint32_t)((kb ^ l7) << 4);
  const uint32_t gsw1 = (uint32_t)(((4 + kb) ^ l7) << 4);
  const uint32_t arow = (uint32_t)(wm * 16384 + lm * 128);
  const uint32_t aoff0 = arow + gsw0, aoff1 = arow + gsw1;
  const uint32_t brow = (BN == 256)
      ? (uint32_t)(wn * 8192 + lm * 128)
      : (uint32_t)((wn >> 1) * 8192 + (wn & 1) * 4096 + lm * 128);
  const uint32_t boff0 = brow + gsw0, boff1 = brow + gsw1;
  const char* AsC = (const char*)As;
  const char* BsC = (const char*)Bs;

  f32x4 acc[8][NI] = {};
  bf16x8 af[2][2][2];       // [regbuf][m2][kk]
  bf16x8 bfr[2][NI][2];     // [tile parity][ni][kk]  -- double-buffered (r6 fix)

  auto ldAf = [&](int dD, int mi, bf16x8* dst) {  // dD, mi compile-time at call
    const uint32_t imA = (uint32_t)((dD * 4 + (mi >> 2)) * 8192 + (mi & 3) * 2048);
    dst[0] = *(const bf16x8*)(AsC + aoff0 + imA);
    dst[1] = *(const bf16x8*)(AsC + aoff1 + imA);
  };
  auto ldBf = [&](int dD) {   // loads tile-dD's B frags into bfr[dD]
#pragma unroll
    for (int ni = 0; ni < NI; ++ni) {
      const uint32_t imB = (uint32_t)(dD * BQ * 8192 + ni * 2048);
      bfr[dD][ni][0] = *(const bf16x8*)(BsC + boff0 + imB);
      bfr[dD][ni][1] = *(const bf16x8*)(BsC + boff1 + imB);
    }
  };
  auto mfma4 = [&](int q, bf16x8 afq[2][2], int dD) {  // q, dD compile-time
    __builtin_amdgcn_s_setprio(1);
#pragma unroll
    for (int kk = 0; kk < 2; ++kk)
#pragma unroll
      for (int ni = 0; ni < NI; ++ni)
#pragma unroll
        for (int m2 = 0; m2 < 2; ++m2)
          acc[q * 2 + m2][ni] = __builtin_amdgcn_mfma_f32_16x16x32_bf16(
              afq[m2][kk], bfr[dD][ni][kk], acc[q * 2 + m2][ni], 0, 0, 0);
    __builtin_amdgcn_s_setprio(0);
  };

  // ---- prologue: stage tile0 full + tile1 {B all, A even-quarters} ----
#pragma unroll
  for (int qa = 0; qa < 4; ++qa)
    gload_lds16(Ab + stat + (size_t)(qa * 64) * KC, As + qa * 4096 + t * 8);
#pragma unroll
  for (int qb = 0; qb < BQ; ++qb)
    gload_lds16(Bb + stat + (size_t)(qb * 64) * KC, Bs + qb * 4096 + t * 8);
#pragma unroll
  for (int qb = 0; qb < BQ; ++qb)
    gload_lds16(Bb + stat + (size_t)(qb * 64) * KC + 64, Bs + (BQ + qb) * 4096 + t * 8);
  gload_lds16(Ab + stat + 64, As + 4 * 4096 + t * 8);
  gload_lds16(Ab + stat + (size_t)128 * KC + 64, As + 6 * 4096 + t * 8);
  if (BN == 256) asm volatile("s_waitcnt vmcnt(6)" ::: "memory");
  else           asm volatile("s_waitcnt vmcnt(4)" ::: "memory");
  __builtin_amdgcn_s_barrier();

  // prefetch tile0 ph0 register fragments
  ldAf(0, 0, af[0][0]); ldAf(0, 1, af[0][1]);
  ldBf(0);
  asm volatile("" ::: "memory");

  // stream pointers positioned at first steady-tile use (kt=0)
  const __bf16* pA0 = Ab + stat + 128;
  const __bf16* pA1 = Ab + stat + (size_t)64 * KC + 64;
  const __bf16* pA2 = Ab + stat + (size_t)128 * KC + 128;
  const __bf16* pA3 = Ab + stat + (size_t)192 * KC + 64;
  const __bf16* pB0 = Bb + stat + 128;
  const __bf16* pB1 = Bb + stat + (size_t)64 * KC + 128;
  const __bf16* pB2 = Bb + stat + (size_t)128 * KC + 128;  // BN256 only
  const __bf16* pB3 = Bb + stat + (size_t)192 * KC + 128;  // BN256 only

  // STG: 2 = steady, 1 = kt==NT-2 (stage A-odd(NT-1) only, vmcnt(0)), 0 = last.
  auto tile = [&](auto Dc, auto Sc) {
    constexpr int D = decltype(Dc)::value;
    constexpr int STG = decltype(Sc)::value;
    // ---------- ph0 ----------
    ldAf(D, 2, af[1][0]); ldAf(D, 3, af[1][1]);
    asm volatile("" ::: "memory");
    if (STG >= 1) {
      gload_lds16(pA1, As + ((D ^ 1) * 4 + 1) * 4096 + t * 8);
      gload_lds16(pA3, As + ((D ^ 1) * 4 + 3) * 4096 + t * 8);
    }
    __builtin_amdgcn_s_barrier();
    mfma4(0, af[0], D);
    __builtin_amdgcn_s_barrier();
    // ---------- ph1 ----------
    ldAf(D, 4, af[0][0]); ldAf(D, 5, af[0][1]);
    asm volatile("" ::: "memory");
    if (STG == 2) {
      gload_lds16(pB0, Bs + (D * BQ + 0) * 4096 + t * 8);
      gload_lds16(pB1, Bs + (D * BQ + 1) * 4096 + t * 8);
    }
    __builtin_amdgcn_s_barrier();
    mfma4(1, af[1], D);
    __builtin_amdgcn_s_barrier();
    // ---------- ph2 ----------
    ldAf(D, 6, af[1][0]); ldAf(D, 7, af[1][1]);
    asm volatile("" ::: "memory");
    if (STG == 2) {
      if (BN == 256) {
        gload_lds16(pB2, Bs + (D * BQ + 2) * 4096 + t * 8);
        gload_lds16(pB3, Bs + (D * BQ + 3) * 4096 + t * 8);
      } else {
        gload_lds16(pA0, As + (D * 4 + 0) * 4096 + t * 8);
        gload_lds16(pA2, As + (D * 4 + 2) * 4096 + t * 8);
      }
    }
    __builtin_amdgcn_s_barrier();
    mfma4(2, af[0], D);
    __builtin_amdgcn_s_barrier();
    // ---------- ph3 ----------
    asm volatile("s_waitcnt lgkmcnt(0)" ::: "memory");
    __builtin_amdgcn_sched_barrier(0);
    if (STG == 2)      asm volatile("s_waitcnt vmcnt(4)" ::: "memory");
    else if (STG == 1) asm volatile("s_waitcnt vmcnt(0)" ::: "memory");
    __builtin_amdgcn_s_barrier();   // publishes tile t+1 (all waves' loads landed)
    if (STG >= 1) {
      ldAf(D ^ 1, 0, af[0][0]); ldAf(D ^ 1, 1, af[0][1]);
      ldBf(D ^ 1);              // -> bfr[D^1]; mfma4(3) below uses bfr[D]
      asm volatile("" ::: "memory");
    }
    if (STG == 2 && BN == 256) {
      gload_lds16(pA0, As + (D * 4 + 0) * 4096 + t * 8);
      gload_lds16(pA2, As + (D * 4 + 2) * 4096 + t * 8);
    }
    __builtin_amdgcn_sched_barrier(0);
    mfma4(3, af[1], D);
    __builtin_amdgcn_s_barrier();
    if (STG == 2) {
      pA0 += 64; pA1 += 64; pA2 += 64; pA3 += 64;
      pB0 += 64; pB1 += 64;
      if (BN == 256) { pB2 += 64; pB3 += 64; }
    }
  };

#pragma unroll 1
  for (int it = 0; it < NT / 2 - 1; ++it) {
    tile(ic<0>{}, ic<2>{});
    tile(ic<1>{}, ic<2>{});
  }
  tile(ic<0>{}, ic<1>{});   // kt = NT-2
  tile(ic<1>{}, ic<0>{});   // kt = NT-1

  // ---- epilogue ----
  const int crow0 = bm0 + wm * 128;
#pragma unroll
  for (int mi = 0; mi < 8; ++mi) {
    if (EPI == 2) {
#pragma unroll
      for (int p = 0; p < NI / 2; ++p) {
        const int ni = p * 2;
        const int col = ((bn0 + wn * 64 + ni * 16) >> 5) * 16 + lm;
#pragma unroll
        for (int r = 0; r < 4; ++r) {
          const int row = crow0 + mi * 16 + kb * 4 + r;
          const float gv = acc[mi][ni][r], uv = acc[mi][ni + 1][r];
          const float av = uv * (gv / (1.0f + __expf(-gv)));
          ((__bf16*)Cv)[(size_t)row * 8192 + col] = (__bf16)av;
        }
      }
    } else {
#pragma unroll
      for (int ni = 0; ni < NI; ++ni) {
        const int col = bn0 + wn * NSTRIP + ni * 16 + lm;
#pragma unroll
        for (int r = 0; r < 4; ++r) {
          const int row = crow0 + mi * 16 + kb * 4 + r;
          const size_t idx = (size_t)row * N + col;
          if (EPI == 0) ((__bf16*)Cv)[idx] = (__bf16)acc[mi][ni][r];
          else          ((float*)Cv)[idx] = addend[idx] + acc[mi][ni][r];
        }
      }
    }
  }
}

extern "C" void kernel_launch(void* const* d_in, const int* in_sizes, int n_in,
                              void* d_out, int out_size, void* d_ws, size_t ws_size,
                              hipStream_t stream) {
  const float* x      = (const float*)d_in[0];
  const float* ln1    = (const float*)d_in[1];
  const float* ln2    = (const float*)d_in[2];
  const int*   qkv_qw = (const int*)d_in[3];
  const int*   qkv_qz = (const int*)d_in[4];
  const float* qkv_sc = (const float*)d_in[5];
  const int*   o_qw   = (const int*)d_in[6];
  const int*   o_qz   = (const int*)d_in[7];
  const float* o_sc   = (const float*)d_in[8];
  const int*   gu_qw  = (const int*)d_in[9];
  const int*   gu_qz  = (const int*)d_in[10];
  const float* gu_sc  = (const float*)d_in[11];
  const int*   dn_qw  = (const int*)d_in[12];
  const int*   dn_qz  = (const int*)d_in[13];
  const float* dn_sc  = (const float*)d_in[14];

  constexpr int M = 4096;

  // Workspace layout (region reuse):
  char* ws = (char*)d_ws;
  __bf16* h   = (__bf16*)(ws + 0);                 // 16 MiB  [4096][2048]
  __bf16* q   = (__bf16*)(ws + 16777216ULL);       // 16 MiB  [4096][2048]
  float*  x2  = (float*)(ws + 33554432ULL);        // 32 MiB  [4096][2048] f32
  __bf16* W   = (__bf16*)(ws + 67108864ULL);       // 64 MiB  weight^T (reused)
  __bf16* act = (__bf16*)(ws + 134217728ULL);      // 64 MiB  [4096][8192]
  __bf16* Wdn = (__bf16*)(ws + 0);                 // 32 MiB  (h,q dead by then)

  // 1. h1 = rmsnorm(x, ln1)
  rmsnorm_kernel<<<dim3(M), dim3(256), 0, stream>>>(x, ln1, h);
  // 2. Wq^T (only first 2048 cols of qkv are used by the reference)
  dequant_t_kernel<0><<<dim3(16, 4), dim3(256), 0, stream>>>(qkv_qw, qkv_qz, qkv_sc, W, 2048, 768, 6144);
  // 3. q = h1 @ Wq
  gemm8p_kernel<128, 0, 2048><<<dim3(256), dim3(512), 0, stream>>>(h, W, (void*)q, nullptr, M, 2048);
  // 4. Wo^T
  dequant_t_kernel<0><<<dim3(16, 4), dim3(256), 0, stream>>>(o_qw, o_qz, o_sc, W, 2048, 256, 2048);
  // 5. x2 = x + q @ Wo
  gemm8p_kernel<128, 1, 2048><<<dim3(256), dim3(512), 0, stream>>>(q, W, (void*)x2, x, M, 2048);
  // 6. h2 = rmsnorm(x2, ln2)
  rmsnorm_kernel<<<dim3(M), dim3(256), 0, stream>>>(x2, ln2, h);
  // 7. Wgu^T [16384][2048], gate/up 16-col interleaved
  dequant_t_kernel<1><<<dim3(16, 32), dim3(256), 0, stream>>>(gu_qw, gu_qz, gu_sc, W, 2048, 2048, 16384);
  // 8. act = silu(gate)*up fused into GEMM epilogue
  gemm8p_kernel<256, 2, 2048><<<dim3(1024), dim3(512), 0, stream>>>(h, W, (void*)act, nullptr, M, 16384);
  // 9. Wdn^T [2048][8192]
  dequant_t_kernel<0><<<dim3(64, 4), dim3(256), 0, stream>>>(dn_qw, dn_qz, dn_sc, Wdn, 8192, 256, 2048);
  // 10. out = x2 + act @ Wdn
  gemm8p_kernel<128, 1, 8192><<<dim3(256), dim3(512), 0, stream>>>(act, Wdn, d_out, x2, M, 2048);
}